// Round 2
// baseline (1078.571 us; speedup 1.0000x reference)
//
#include <hip/hip_runtime.h>
#include <stdint.h>
#include <type_traits>

// Problem constants: B=32, L=4096, C=512, H=8, S=8, NW=512, D=64
// M = B*L = 131072 rows. I/O is fp32 (per reference); internal compute bf16.

typedef unsigned short ushort_t;
typedef __bf16 v8bf __attribute__((ext_vector_type(8)));
typedef float v4f __attribute__((ext_vector_type(4)));

__device__ __forceinline__ ushort_t f2bf(float f) {
  unsigned int u = __float_as_uint(f);
  u = u + 0x7fffu + ((u >> 16) & 1u);   // RNE
  return (ushort_t)(u >> 16);
}

// ---------------- prep: transpose fp32 weights -> bf16 B^T, fused qkv bias ---
__global__ __launch_bounds__(256) void prep_kernel(
    const float* __restrict__ Wq, const float* __restrict__ Wk,
    const float* __restrict__ Wv, const float* __restrict__ Wp,
    const float* __restrict__ bq, const float* __restrict__ bk,
    const float* __restrict__ bv,
    ushort_t* __restrict__ WTqkv, ushort_t* __restrict__ WTp,
    float* __restrict__ bqkvf)
{
  int idx = blockIdx.x * 256 + threadIdx.x;
  if (idx < 786432) {                       // WTqkv[n][k] = W_{q,k,v}[k][n&511]
    int n = idx % 1536;
    int k = idx / 1536;
    const float* W = (n < 512) ? Wq : (n < 1024) ? Wk : Wv;
    WTqkv[(size_t)n * 512 + k] = f2bf(W[k * 512 + (n & 511)]);
  } else if (idx < 1048576) {               // WTp[n][k] = Wp[k][n]
    int j = idx - 786432;
    int n = j & 511;
    int k = j >> 9;
    WTp[(size_t)n * 512 + k] = f2bf(Wp[k * 512 + n]);
  } else if (idx < 1050112) {               // fused qkv bias (fp32)
    int n = idx - 1048576;
    const float* bb = (n < 512) ? bq : (n < 1024) ? bk : bv;
    bqkvf[n] = bb[n & 511];
  }
}

// ---------------- convert fp32 x -> bf16, roll(x,-4) folded into row remap ---
__global__ __launch_bounds__(256) void convert_roll_kernel(
    const float* __restrict__ x, ushort_t* __restrict__ xb)
{
  const int t = blockIdx.x * 256 + threadIdx.x;   // 8,388,608 threads
  const int m = t >> 6;                           // dest row (rolled space)
  const int ch = t & 63;                          // 8-element chunk
  const int b = m >> 12;
  const int r = m & 4095;
  const int src = (b << 12) | ((r + 4) & 4095);
  const float4* p = (const float4*)(x + (size_t)src * 512 + ch * 8);
  float4 a0 = p[0], a1 = p[1];
  uint4 o;
  o.x = (unsigned)f2bf(a0.x) | ((unsigned)f2bf(a0.y) << 16);
  o.y = (unsigned)f2bf(a0.z) | ((unsigned)f2bf(a0.w) << 16);
  o.z = (unsigned)f2bf(a1.x) | ((unsigned)f2bf(a1.y) << 16);
  o.w = (unsigned)f2bf(a1.z) | ((unsigned)f2bf(a1.w) << 16);
  *(uint4*)(xb + (size_t)m * 512 + ch * 8) = o;
}

// ---------------- bf16 GEMM: C[m][n] = A[m][:] . BT[n][:] + bias[n] ----------
// 128x128 tile, BK=64, 256 threads = 4 waves (2x2), each wave 64x64 via 4x4
// mfma_f32_16x16x32_bf16. global_load_lds width-16 staging (contiguous lane
// order -> no LDS padding). NT tiles of N looped per block so the A slice
// stays cache-resident. ROLL_C remaps C rows by +4 mod 4096 (roll(out,+4)).
template<int LDC, int NT, bool ROLL_C, typename OutT>
__global__ __launch_bounds__(256) void gemm_bt(
    const ushort_t* __restrict__ A, const ushort_t* __restrict__ BT,
    const float* __restrict__ bias, OutT* __restrict__ C)
{
  __shared__ __align__(16) ushort_t As[128 * 64];
  __shared__ __align__(16) ushort_t Bs[128 * 64];

  const int tid = threadIdx.x;
  const int l   = tid & 63;
  const int wv  = tid >> 6;
  const int wm  = wv >> 1;          // wave row (0..1)
  const int wn  = wv & 1;           // wave col (0..1)

  const int m0    = blockIdx.y * 128;
  const int nbase = blockIdx.x * (NT * 128);

  const int skcol   = (l & 7) * 8;          // k offset of this lane's 16B chunk
  const int lds_off = wv * 512 + l * 8;     // + p*2048 (elements)
  const int fr = l & 15;                    // fragment row/col within 16
  const int fq = l >> 4;                    // quad (k group / acc row group)

  for (int nt = 0; nt < NT; ++nt) {
    const int n0 = nbase + nt * 128;
    v4f acc[4][4];
#pragma unroll
    for (int i = 0; i < 4; ++i)
#pragma unroll
      for (int j = 0; j < 4; ++j) acc[i][j] = (v4f){0.f, 0.f, 0.f, 0.f};

    for (int kt = 0; kt < 8; ++kt) {
      const int k0 = kt * 64;
      __syncthreads();
#pragma unroll
      for (int p = 0; p < 4; ++p) {
        const int gm = m0 + p * 32 + wv * 8 + (l >> 3);
        const ushort_t* ap = A + (size_t)gm * 512 + k0 + skcol;
        __builtin_amdgcn_global_load_lds(
            (const __attribute__((address_space(1))) void*)ap,
            (__attribute__((address_space(3))) void*)(As + p * 2048 + lds_off),
            16, 0, 0);
        const int gn = n0 + p * 32 + wv * 8 + (l >> 3);
        const ushort_t* bp = BT + (size_t)gn * 512 + k0 + skcol;
        __builtin_amdgcn_global_load_lds(
            (const __attribute__((address_space(1))) void*)bp,
            (__attribute__((address_space(3))) void*)(Bs + p * 2048 + lds_off),
            16, 0, 0);
      }
      __syncthreads();
#pragma unroll
      for (int kk = 0; kk < 2; ++kk) {
        const int ko = kk * 32 + fq * 8;
        v8bf af[4], bf[4];
#pragma unroll
        for (int mi = 0; mi < 4; ++mi)
          af[mi] = *(const v8bf*)(As + (wm * 64 + mi * 16 + fr) * 64 + ko);
#pragma unroll
        for (int ni = 0; ni < 4; ++ni)
          bf[ni] = *(const v8bf*)(Bs + (wn * 64 + ni * 16 + fr) * 64 + ko);
#pragma unroll
        for (int mi = 0; mi < 4; ++mi)
#pragma unroll
          for (int ni = 0; ni < 4; ++ni)
            acc[mi][ni] = __builtin_amdgcn_mfma_f32_16x16x32_bf16(
                af[mi], bf[ni], acc[mi][ni], 0, 0, 0);
      }
    }

    // epilogue: C/D layout col = lane&15, row = (lane>>4)*4 + r  [m89/m91]
#pragma unroll
    for (int mi = 0; mi < 4; ++mi) {
#pragma unroll
      for (int ni = 0; ni < 4; ++ni) {
        const int col = n0 + wn * 64 + ni * 16 + fr;
        const float bv = bias[col];
#pragma unroll
        for (int r = 0; r < 4; ++r) {
          int row = m0 + wm * 64 + mi * 16 + fq * 4 + r;
          if (ROLL_C) row = (row & ~4095) | ((row + 4) & 4095);
          const float val = acc[mi][ni][r] + bv;
          if constexpr (std::is_same_v<OutT, float>) {
            C[(size_t)row * LDC + col] = val;
          } else {
            C[(size_t)row * LDC + col] = f2bf(val);
          }
        }
      }
    }
  }
}

// ---------------- attention: one wave per (batch, window, head) --------------
// qkv layout: [B*L][1536] rolled rows; cols 0..511=Q, 512..1023=K, 1024..1535=V
__device__ __forceinline__ void unpack8(uint4 v, float* f) {
  f[0] = __uint_as_float(v.x << 16); f[1] = __uint_as_float(v.x & 0xffff0000u);
  f[2] = __uint_as_float(v.y << 16); f[3] = __uint_as_float(v.y & 0xffff0000u);
  f[4] = __uint_as_float(v.z << 16); f[5] = __uint_as_float(v.z & 0xffff0000u);
  f[6] = __uint_as_float(v.w << 16); f[7] = __uint_as_float(v.w & 0xffff0000u);
}

__global__ __launch_bounds__(256) void attn_kernel(
    const ushort_t* __restrict__ qkv, const float* __restrict__ bias_table,
    ushort_t* __restrict__ attout)
{
  __shared__ float btab[120];                 // (2S-1) x H fp32
  if (threadIdx.x < 120) btab[threadIdx.x] = bias_table[threadIdx.x];
  __syncthreads();

  const int l  = threadIdx.x & 63;
  const int wv = threadIdx.x >> 6;
  const int u  = blockIdx.x * 4 + wv;         // window-head id
  const int b  = u >> 12;                     // NW*H = 4096
  const int w  = (u >> 3) & 511;
  const int h  = u & 7;
  const int i  = l >> 3;                      // query row in window
  const int c  = l & 7;                       // 8-element d-chunk

  const size_t rowi = (size_t)(b << 12) + (w << 3) + i;
  const ushort_t* pq = qkv + rowi * 1536 + h * 64 + c * 8;
  uint4 q8 = *(const uint4*)pq;
  uint4 k8 = *(const uint4*)(pq + 512);
  uint4 v8 = *(const uint4*)(pq + 1024);

  float qf[8];
  unpack8(q8, qf);

  // energy[i][j], j = (i+t)&7 held in e[t]; rotation via shfl (l+8t)&63
  float e[8];
#pragma unroll
  for (int t = 0; t < 8; ++t) {
    const int src = (l + 8 * t) & 63;
    uint4 kc;
    kc.x = __shfl((int)k8.x, src); kc.y = __shfl((int)k8.y, src);
    kc.z = __shfl((int)k8.z, src); kc.w = __shfl((int)k8.w, src);
    float kf[8]; unpack8(kc, kf);
    float s = 0.f;
#pragma unroll
    for (int d = 0; d < 8; ++d) s = fmaf(qf[d], kf[d], s);
    s += __shfl_xor(s, 1);                    // butterfly over c (3 steps)
    s += __shfl_xor(s, 2);
    s += __shfl_xor(s, 4);
    e[t] = s;
  }

  const float scale = 0.044194173824159216f;  // 1/sqrt(C=512)
#pragma unroll
  for (int t = 0; t < 8; ++t) {
    const int j = (i + t) & 7;
    float ev = e[t] * scale + btab[(j - i + 7) * 8 + h];
    if (w == 511 && ((i < 4) != (j < 4))) ev -= 100.f;  // shift mask
    e[t] = ev;
  }

  float mx = e[0];
#pragma unroll
  for (int t = 1; t < 8; ++t) mx = fmaxf(mx, e[t]);
  float p[8], sum = 0.f;
#pragma unroll
  for (int t = 0; t < 8; ++t) { p[t] = __expf(e[t] - mx); sum += p[t]; }
  const float inv = __fdividef(1.f, sum);

  float of[8] = {0.f, 0.f, 0.f, 0.f, 0.f, 0.f, 0.f, 0.f};
#pragma unroll
  for (int t = 0; t < 8; ++t) {
    const int src = (l + 8 * t) & 63;
    uint4 vc;
    vc.x = __shfl((int)v8.x, src); vc.y = __shfl((int)v8.y, src);
    vc.z = __shfl((int)v8.z, src); vc.w = __shfl((int)v8.w, src);
    float vf[8]; unpack8(vc, vf);
    const float a = p[t] * inv;
#pragma unroll
    for (int d = 0; d < 8; ++d) of[d] = fmaf(a, vf[d], of[d]);
  }

  uint4 o;
  o.x = (unsigned)f2bf(of[0]) | ((unsigned)f2bf(of[1]) << 16);
  o.y = (unsigned)f2bf(of[2]) | ((unsigned)f2bf(of[3]) << 16);
  o.z = (unsigned)f2bf(of[4]) | ((unsigned)f2bf(of[5]) << 16);
  o.w = (unsigned)f2bf(of[6]) | ((unsigned)f2bf(of[7]) << 16);
  *(uint4*)(attout + rowi * 512 + h * 64 + c * 8) = o;
}

// ---------------- launcher ---------------------------------------------------
extern "C" void kernel_launch(void* const* d_in, const int* in_sizes, int n_in,
                              void* d_out, int out_size, void* d_ws, size_t ws_size,
                              hipStream_t stream) {
  (void)in_sizes; (void)n_in; (void)out_size; (void)ws_size;
  const float* x  = (const float*)d_in[0];
  const float* Wq = (const float*)d_in[1];
  const float* bq = (const float*)d_in[2];
  const float* Wk = (const float*)d_in[3];
  const float* bk = (const float*)d_in[4];
  const float* Wv = (const float*)d_in[5];
  const float* bv = (const float*)d_in[6];
  const float* Wp = (const float*)d_in[7];
  const float* bp = (const float*)d_in[8];
  const float* bt = (const float*)d_in[9];

  char* ws = (char*)d_ws;
  ushort_t* qkv    = (ushort_t*)(ws);                    // 131072*1536*2 = 402,653,184
  ushort_t* xb     = (ushort_t*)(ws + 402653184ull);     // 131072*512*2  = 134,217,728
  ushort_t* attout = xb;                                 // reuse: xb dead after QKV GEMM
  ushort_t* WTqkv  = (ushort_t*)(ws + 536870912ull);     // 1536*512*2
  ushort_t* WTp    = (ushort_t*)(ws + 538443776ull);     // 512*512*2
  float*    bqkvf  = (float*)  (ws + 538968064ull);      // 1536*4

  prep_kernel<<<4103, 256, 0, stream>>>(Wq, Wk, Wv, Wp, bq, bk, bv,
                                        WTqkv, WTp, bqkvf);
  // fp32 -> bf16 with roll(x,-4) folded in
  convert_roll_kernel<<<32768, 256, 0, stream>>>(x, xb);
  // QKV projection (bf16 out)
  gemm_bt<1536, 4, false, ushort_t><<<dim3(3, 1024), 256, 0, stream>>>(
      xb, WTqkv, bqkvf, qkv);
  // windowed attention
  attn_kernel<<<32768, 256, 0, stream>>>(qkv, bt, attout);
  // output projection, fp32 out, roll(+4) folded into C-row remap
  gemm_bt<512, 2, true, float><<<dim3(2, 1024), 256, 0, stream>>>(
      attout, WTp, bp, (float*)d_out);
}